// Round 8
// baseline (208.546 us; speedup 1.0000x reference)
//
#include <hip/hip_runtime.h>
#include <hip/hip_bf16.h>
#include <math.h>

typedef __bf16 bf16_t;
typedef __attribute__((ext_vector_type(8))) __bf16 bf16x8;
typedef __attribute__((ext_vector_type(4))) __bf16 bf16x4;
typedef __attribute__((ext_vector_type(4))) float f32x4;

#define MFMA_16x16x32(A_, B_, C_) __builtin_amdgcn_mfma_f32_16x16x32_bf16((A_), (B_), (C_), 0, 0, 0)

#define Bsz 4
#define Ssz 2048
#define Dsz 1024
#define Hh 16
#define DKd 64
#define Mrows (Bsz * Ssz)  /* 8192 */
#define N1 (3 * Dsz)       /* 3072 */
#define KD Dsz             /* 1024 */

// ---------------- f32 -> bf16 conversion (x4 vectorized) ----------------
__global__ void cvt_f32_bf16_kernel(const float* __restrict__ src, bf16_t* __restrict__ dst, int n4) {
  int i = blockIdx.x * blockDim.x + threadIdx.x;
  if (i >= n4) return;
  float4 v = reinterpret_cast<const float4*>(src)[i];
  bf16x4 o = {(bf16_t)v.x, (bf16_t)v.y, (bf16_t)v.z, (bf16_t)v.w};
  reinterpret_cast<bf16x4*>(dst)[i] = o;
}

// ---------------- RoPE cos/sin table: [S][32] float2 ----------------
__global__ void rope_tab_kernel(const int* __restrict__ pos, float2* __restrict__ tab) {
  int i = blockIdx.x * blockDim.x + threadIdx.x;
  if (i >= Ssz * 32) return;
  int s = i >> 5, f = i & 31;
  float inv_freq = powf(10000.0f, -(float)(2 * f) / 64.0f);
  float a = (float)pos[s] * inv_freq;
  tab[i] = make_float2(cosf(a), sinf(a));
}

// ============ QKV GEMM: 256x256 tile, BK=32 steps, 4-deep LDS ring ============
// Ring: compute step s from buf[s&3], stage s+3 into buf[(s+3)&3]; loads span
// 3 barriers. Counted s_waitcnt vmcnt(8) (never 0 in steady state) + raw
// s_barrier (NOT __syncthreads -> would force vmcnt(0) drain). 32 MFMA + 12
// ds_read_b128 per step per wave; setprio around the MFMA cluster.
// Swizzle: LDS chunk c of row r holds global chunk c ^ ((r>>1)&3); read side
// applies the same XOR (lane-invariant form (lr>>1)&3 since frag rows are
// 16-aligned). Bank load even (4 lanes / 4-bank group = b128 floor).
__global__ __launch_bounds__(512, 1) void gemm256_qkv_kernel(
    const bf16_t* __restrict__ A, const bf16_t* __restrict__ Bt,
    bf16_t* __restrict__ qb, bf16_t* __restrict__ kb, bf16_t* __restrict__ vtb,
    const float2* __restrict__ tab) {
  constexpr int NSTEPS = KD / 32;  // 32
  __shared__ __align__(16) bf16_t As[4][256 * 32];
  __shared__ __align__(16) bf16_t Bs[4][256 * 32];
  const int t = threadIdx.x;
  const int w = t >> 6, l = t & 63;
  const int lr = l & 15, lk = l >> 4;
  const int wm = w >> 2, wn = w & 3;  // 2M x 4N waves
  const int m0 = blockIdx.y * 256, n0 = blockIdx.x * 256;

  // staging: thread t -> row t>>2 (and +128), LDS chunk t&3 holding global
  // chunk (t&3) ^ ((row>>1)&3) = (t&3) ^ ((t>>3)&3). Lane-linear LDS dest.
  const int gcol = ((t & 3) ^ ((t >> 3) & 3)) * 8;
  const bf16_t* gA0 = A + (size_t)(m0 + (t >> 2)) * KD + gcol;
  const bf16_t* gA1 = gA0 + (size_t)128 * KD;
  const bf16_t* gB0 = Bt + (size_t)(n0 + (t >> 2)) * KD + gcol;
  const bf16_t* gB1 = gB0 + (size_t)128 * KD;
  const int ldsoff0 = w * 512;         // elem offset of wave's linear region
  const int ldsoff1 = 4096 + w * 512;  // rows 128..255

  // loop-invariant fragment read offsets (elems)
  int aOffE[8], bOffE[4];
  const int rxor = (lr >> 1) & 3;
#pragma unroll
  for (int m = 0; m < 8; ++m)
    aOffE[m] = (wm * 128 + m * 16 + lr) * 32 + ((lk ^ rxor) * 8);
#pragma unroll
  for (int n = 0; n < 4; ++n)
    bOffE[n] = (wn * 64 + n * 16 + lr) * 32 + ((lk ^ rxor) * 8);

  f32x4 acc[8][4] = {};

  // prologue: stage steps 0,1,2
#pragma unroll
  for (int i = 0; i < 3; ++i) {
    __builtin_amdgcn_global_load_lds(gA0 + i * 32, &As[i][ldsoff0], 16, 0, 0);
    __builtin_amdgcn_global_load_lds(gA1 + i * 32, &As[i][ldsoff1], 16, 0, 0);
    __builtin_amdgcn_global_load_lds(gB0 + i * 32, &Bs[i][ldsoff0], 16, 0, 0);
    __builtin_amdgcn_global_load_lds(gB1 + i * 32, &Bs[i][ldsoff1], 16, 0, 0);
  }

#define K_STEP_BODY(S_, VMSTR_)                                                      \
  do {                                                                               \
    asm volatile(VMSTR_ ::: "memory");                                               \
    __builtin_amdgcn_s_barrier();                                                    \
    __builtin_amdgcn_sched_barrier(0);                                               \
    if ((S_) + 3 < NSTEPS) {                                                         \
      const int rb_ = ((S_) + 3) & 3;                                                \
      const int kt_ = ((S_) + 3) * 32;                                               \
      __builtin_amdgcn_global_load_lds(gA0 + kt_, &As[rb_][ldsoff0], 16, 0, 0);      \
      __builtin_amdgcn_global_load_lds(gA1 + kt_, &As[rb_][ldsoff1], 16, 0, 0);      \
      __builtin_amdgcn_global_load_lds(gB0 + kt_, &Bs[rb_][ldsoff0], 16, 0, 0);      \
      __builtin_amdgcn_global_load_lds(gB1 + kt_, &Bs[rb_][ldsoff1], 16, 0, 0);      \
    }                                                                                \
    const bf16_t* Ab_ = As[(S_) & 3];                                                \
    const bf16_t* Bb_ = Bs[(S_) & 3];                                                \
    bf16x8 af_[8], bf_[4];                                                           \
    _Pragma("unroll") for (int n_ = 0; n_ < 4; ++n_) bf_[n_] =                       \
        *reinterpret_cast<const bf16x8*>(Bb_ + bOffE[n_]);                           \
    _Pragma("unroll") for (int m_ = 0; m_ < 8; ++m_) af_[m_] =                       \
        *reinterpret_cast<const bf16x8*>(Ab_ + aOffE[m_]);                           \
    __builtin_amdgcn_s_setprio(1);                                                   \
    _Pragma("unroll") for (int m_ = 0; m_ < 8; ++m_)                                 \
      _Pragma("unroll") for (int n_ = 0; n_ < 4; ++n_)                               \
          acc[m_][n_] = MFMA_16x16x32(af_[m_], bf_[n_], acc[m_][n_]);                \
    __builtin_amdgcn_s_setprio(0);                                                   \
  } while (0)

#pragma unroll 1
  for (int s = 0; s < NSTEPS - 2; ++s) K_STEP_BODY(s, "s_waitcnt vmcnt(8)");
  K_STEP_BODY(NSTEPS - 2, "s_waitcnt vmcnt(4)");
  K_STEP_BODY(NSTEPS - 1, "s_waitcnt vmcnt(0)");
#undef K_STEP_BODY

  // ---- epilogue: RoPE for q/k, transposed scatter for v ----
  const int sect = n0 >> 10;                  // uniform per block
  const int hh = ((n0 + wn * 64) >> 6) & 15;  // uniform per wave
  if (sect < 2) {
#pragma unroll
    for (int m = 0; m < 8; ++m)
#pragma unroll
      for (int r = 0; r < 4; ++r) {
        const int grow = m0 + wm * 128 + m * 16 + lk * 4 + r;
        const int bb = grow >> 11, s = grow & (Ssz - 1);
        const float2* tr = tab + (s << 5);
        bf16_t* basep = (sect == 0 ? qb : kb) + ((size_t)(bb * Hh + hh) * Ssz + s) * DKd;
#pragma unroll
        for (int n = 0; n < 4; ++n) {
          const float v = acc[m][n][r];
          const float pv = __shfl_xor(v, 1);
          const int dk = n * 16 + lr;
          const float2 cs = tr[dk >> 1];
          float vr = (dk & 1) ? (pv * cs.y + v * cs.x) : (v * cs.x - pv * cs.y);
          if (sect == 0) vr *= 0.125f;
          basep[dk] = (bf16_t)vr;
        }
      }
  } else {
#pragma unroll
    for (int m = 0; m < 8; ++m)
#pragma unroll
      for (int r = 0; r < 4; ++r) {
        const int grow = m0 + wm * 128 + m * 16 + lk * 4 + r;
        const int bb = grow >> 11, s = grow & (Ssz - 1);
        bf16_t* vb = vtb + (size_t)(bb * Hh + hh) * DKd * Ssz + s;
#pragma unroll
        for (int n = 0; n < 4; ++n)
          vb[(size_t)(n * 16 + lr) * Ssz] = (bf16_t)acc[m][n][r];
      }
  }
}

// ---------------- out-proj GEMM: 128x128 m97 structure (unchanged) -------
__global__ __launch_bounds__(256, 3) void gemm_out_kernel(
    const bf16_t* __restrict__ A, const bf16_t* __restrict__ Bt, int Kdim, int ldcN,
    float* __restrict__ fout) {
  __shared__ __align__(16) bf16_t As[2][128 * 32];
  __shared__ __align__(16) bf16_t Bs[2][128 * 32];
  const int t = threadIdx.x;
  const int w = t >> 6, l = t & 63;
  const int lr = l & 15, lk = l >> 4;
  const int wm = w >> 1, wn = w & 1;
  const int m0 = blockIdx.y * 128, n0 = blockIdx.x * 128;

  const int srow = t >> 2;
  const int schunk = (t & 3) ^ ((t >> 3) & 3);
  const bf16_t* gA = A + (size_t)(m0 + srow) * Kdim + schunk * 8;
  const bf16_t* gB = Bt + (size_t)(n0 + srow) * Kdim + schunk * 8;

  f32x4 acc[4][4] = {};
  const int rsw = (lr >> 1) & 3;

#define STAGE_(PH, KT)                                                                   \
  do {                                                                                   \
    __builtin_amdgcn_global_load_lds(gA + (KT), &As[PH][(w * 16) * 32], 16, 0, 0);       \
    __builtin_amdgcn_global_load_lds(gA + (size_t)64 * Kdim + (KT),                      \
                                     &As[PH][(64 + w * 16) * 32], 16, 0, 0);             \
    __builtin_amdgcn_global_load_lds(gB + (KT), &Bs[PH][(w * 16) * 32], 16, 0, 0);       \
    __builtin_amdgcn_global_load_lds(gB + (size_t)64 * Kdim + (KT),                      \
                                     &Bs[PH][(64 + w * 16) * 32], 16, 0, 0);             \
  } while (0)

#define COMPUTE_(PH)                                                                     \
  do {                                                                                   \
    bf16x8 af[4], bfv[4];                                                                \
    _Pragma("unroll") for (int m = 0; m < 4; ++m) af[m] =                                \
        *reinterpret_cast<const bf16x8*>(&As[PH][(wm * 64 + m * 16 + lr) * 32] +         \
                                         ((lk ^ rsw) * 8));                              \
    _Pragma("unroll") for (int n = 0; n < 4; ++n) bfv[n] =                               \
        *reinterpret_cast<const bf16x8*>(&Bs[PH][(wn * 64 + n * 16 + lr) * 32] +         \
                                         ((lk ^ rsw) * 8));                              \
    _Pragma("unroll") for (int m = 0; m < 4; ++m) _Pragma("unroll") for (int n = 0;      \
                                                                         n < 4; ++n)    \
        acc[m][n] = MFMA_16x16x32(af[m], bfv[n], acc[m][n]);                             \
  } while (0)

  STAGE_(0, 0);
  __syncthreads();
  for (int kt = 0; kt < Kdim; kt += 64) {
    STAGE_(1, kt + 32);
    COMPUTE_(0);
    __syncthreads();
    if (kt + 64 < Kdim) STAGE_(0, kt + 64);
    COMPUTE_(1);
    __syncthreads();
  }
#undef STAGE_
#undef COMPUTE_

#pragma unroll
  for (int m = 0; m < 4; ++m)
#pragma unroll
    for (int r = 0; r < 4; ++r) {
      const int grow = m0 + wm * 64 + m * 16 + lk * 4 + r;
      float* op = fout + (size_t)grow * ldcN + n0 + wn * 64 + lr;
#pragma unroll
      for (int n = 0; n < 4; ++n) op[n * 16] = acc[m][n][r];
    }
}

// ---------------- causal flash attention, swapped-QK^T / in-lane softmax ----
__global__ __launch_bounds__(256, 3) void attn_kernel(
    const bf16_t* __restrict__ qb, const bf16_t* __restrict__ kb,
    const bf16_t* __restrict__ vtb, bf16_t* __restrict__ aout) {
  __shared__ __align__(16) bf16_t Ks[64 * 64];
  __shared__ __align__(16) bf16_t Vs[64 * 64];
  const int t = threadIdx.x, w = t >> 6, l = t & 63;
  const int lr = l & 15, lk = l >> 4;
  const int bid = blockIdx.x;
  const int bh = (bid & 7) * 8 + ((bid >> 3) & 7);
  const int qt = 15 - (bid >> 6);  // heavy-first
  const int q0 = qt * 128;
  const int sub0 = q0 + w * 32;

  const bf16_t* qbase = qb + ((size_t)bh * Ssz + sub0) * DKd;
  bf16x8 qf[2][2];
#pragma unroll
  for (int s = 0; s < 2; ++s) {
    qf[s][0] = *reinterpret_cast<const bf16x8*>(qbase + (s * 16 + lr) * DKd + lk * 8);
    qf[s][1] = *reinterpret_cast<const bf16x8*>(qbase + (s * 16 + lr) * DKd + 32 + lk * 8);
  }

  f32x4 o[2][4] = {};
  float mrow[2] = {-INFINITY, -INFINITY};
  float lsum[2] = {0.f, 0.f};

  const int srow = t >> 2;
  const int scc = (t & 3) * 2;
  const bf16_t* kg = kb + ((size_t)bh * Ssz + srow) * DKd + scc * 8;
  const bf16_t* vg = vtb + ((size_t)bh * DKd + srow) * Ssz + scc * 8;
  bf16_t* ksw0 = Ks + srow * 64 + ((scc ^ (srow & 7)) * 8);
  bf16_t* ksw1 = Ks + srow * 64 + (((scc + 1) ^ (srow & 7)) * 8);
  bf16_t* vw[4];
#pragma unroll
  for (int u = 0; u < 2; ++u) {
    const int c = scc + u;
    const int B = 32 * (c >> 2) + 16 * (c & 1) + 4 * ((c & 3) >> 1);
    const int ch = B >> 3, off = B & 7;
    vw[2 * u] = Vs + srow * 64 + ((ch ^ (srow & 7)) * 8) + off;
    vw[2 * u + 1] = Vs + srow * 64 + (((ch + 1) ^ (srow & 7)) * 8) + off;
  }

  const int kvend = q0 + 128;
  bf16x8 pk0 = *reinterpret_cast<const bf16x8*>(kg);
  bf16x8 pk1 = *reinterpret_cast<const bf16x8*>(kg + 8);
  bf16x8 pv0 = *reinterpret_cast<const bf16x8*>(vg);
  bf16x8 pv1 = *reinterpret_cast<const bf16x8*>(vg + 8);

  for (int kv = 0; kv < kvend; kv += 64) {
    __syncthreads();
    *reinterpret_cast<bf16x8*>(ksw0) = pk0;
    *reinterpret_cast<bf16x8*>(ksw1) = pk1;
    *reinterpret_cast<bf16x4*>(vw[0]) = __builtin_shufflevector(pv0, pv0, 0, 1, 2, 3);
    *reinterpret_cast<bf16x4*>(vw[1]) = __builtin_shufflevector(pv0, pv0, 4, 5, 6, 7);
    *reinterpret_cast<bf16x4*>(vw[2]) = __builtin_shufflevector(pv1, pv1, 0, 1, 2, 3);
    *reinterpret_cast<bf16x4*>(vw[3]) = __builtin_shufflevector(pv1, pv1, 4, 5, 6, 7);
    __syncthreads();
    if (kv + 64 < kvend) {
      pk0 = *reinterpret_cast<const bf16x8*>(kg + (size_t)(kv + 64) * DKd);
      pk1 = *reinterpret_cast<const bf16x8*>(kg + (size_t)(kv + 64) * DKd + 8);
      pv0 = *reinterpret_cast<const bf16x8*>(vg + kv + 64);
      pv1 = *reinterpret_cast<const bf16x8*>(vg + kv + 64 + 8);
    }
#pragma unroll
    for (int s = 0; s < 2; ++s) {
      const int subrow = sub0 + s * 16;
      if (kv > subrow + 15) continue;
      f32x4 sa[4];
#pragma unroll
      for (int n = 0; n < 4; ++n) {
        const int R = n * 16 + lr;
        const bf16x8 a0 = *reinterpret_cast<const bf16x8*>(Ks + R * 64 + ((lk ^ (R & 7)) * 8));
        const bf16x8 a1 = *reinterpret_cast<const bf16x8*>(Ks + R * 64 + (((lk + 4) ^ (R & 7)) * 8));
        f32x4 z = {};
        z = MFMA_16x16x32(a0, qf[s][0], z);
        z = MFMA_16x16x32(a1, qf[s][1], z);
        sa[n] = z;
      }
      if (kv + 63 > subrow) {
        const int qrow = subrow + lr;
        const int kbase = kv + lk * 4;
#pragma unroll
        for (int n = 0; n < 4; ++n)
#pragma unroll
          for (int r = 0; r < 4; ++r)
            if (kbase + n * 16 + r > qrow) sa[n][r] = -INFINITY;
      }
      float mx = fmaxf(fmaxf(fmaxf(sa[0][0], sa[0][1]), fmaxf(sa[0][2], sa[0][3])),
                       fmaxf(fmaxf(sa[1][0], sa[1][1]), fmaxf(sa[1][2], sa[1][3])));
      mx = fmaxf(mx, fmaxf(fmaxf(fmaxf(sa[2][0], sa[2][1]), fmaxf(sa[2][2], sa[2][3])),
                           fmaxf(fmaxf(sa[3][0], sa[3][1]), fmaxf(sa[3][2], sa[3][3]))));
      mx = fmaxf(mx, __shfl_xor(mx, 16));
      mx = fmaxf(mx, __shfl_xor(mx, 32));
      const float mnew = fmaxf(mrow[s], mx);
      const float scl = __expf(mrow[s] - mnew);
      mrow[s] = mnew;
      float ps = 0.f;
#pragma unroll
      for (int n = 0; n < 4; ++n)
#pragma unroll
        for (int r = 0; r < 4; ++r) {
          const float p = __expf(sa[n][r] - mnew);
          sa[n][r] = p;
          ps += p;
        }
      lsum[s] = lsum[s] * scl + ps;
#pragma unroll
      for (int n = 0; n < 4; ++n)
#pragma unroll
        for (int r = 0; r < 4; ++r) o[s][n][r] *= scl;
      bf16x8 pb0, pb1;
#pragma unroll
      for (int r = 0; r < 4; ++r) {
        pb0[r] = (bf16_t)sa[0][r];
        pb0[4 + r] = (bf16_t)sa[1][r];
        pb1[r] = (bf16_t)sa[2][r];
        pb1[4 + r] = (bf16_t)sa[3][r];
      }
#pragma unroll
      for (int n = 0; n < 4; ++n) {
        const int R = n * 16 + lr;
        const bf16x8 v0 = *reinterpret_cast<const bf16x8*>(Vs + R * 64 + ((lk ^ (R & 7)) * 8));
        const bf16x8 v1 = *reinterpret_cast<const bf16x8*>(Vs + R * 64 + (((lk + 4) ^ (R & 7)) * 8));
        o[s][n] = MFMA_16x16x32(v0, pb0, o[s][n]);
        o[s][n] = MFMA_16x16x32(v1, pb1, o[s][n]);
      }
    }
  }
  const int b_ = bh >> 4, h_ = bh & 15;
#pragma unroll
  for (int s = 0; s < 2; ++s) {
    float sm = lsum[s];
    sm += __shfl_xor(sm, 16);
    sm += __shfl_xor(sm, 32);
    const float inv = 1.0f / sm;
    const int qrow = sub0 + s * 16 + lr;
    bf16_t* op = aout + ((size_t)b_ * Ssz + qrow) * Dsz + h_ * DKd + lk * 4;
#pragma unroll
    for (int n = 0; n < 4; ++n) {
      const bf16x4 ov = {(bf16_t)(o[s][n][0] * inv), (bf16_t)(o[s][n][1] * inv),
                         (bf16_t)(o[s][n][2] * inv), (bf16_t)(o[s][n][3] * inv)};
      *reinterpret_cast<bf16x4*>(op + n * 16) = ov;
    }
  }
}

extern "C" void kernel_launch(void* const* d_in, const int* in_sizes, int n_in,
                              void* d_out, int out_size, void* d_ws, size_t ws_size,
                              hipStream_t stream) {
  const float* x = (const float*)d_in[0];
  const int* pos = (const int*)d_in[1];
  const float* wqkv = (const float*)d_in[2];
  const float* wo = (const float*)d_in[3];
  float* out = (float*)d_out;

  bf16_t* xb = (bf16_t*)d_ws;
  bf16_t* wqkvb = xb + (size_t)Mrows * KD;
  bf16_t* wob = wqkvb + (size_t)N1 * KD;
  bf16_t* qbuf = wob + (size_t)Dsz * KD;
  bf16_t* kbuf = qbuf + (size_t)64 * Ssz * DKd;
  bf16_t* vtb = kbuf + (size_t)64 * Ssz * DKd;
  float2* tab = (float2*)(vtb + (size_t)64 * Ssz * DKd);
  bf16_t* aout = xb;

  {
    int n4 = Mrows * KD / 4;
    cvt_f32_bf16_kernel<<<(n4 + 255) / 256, 256, 0, stream>>>(x, xb, n4);
  }
  {
    int n4 = N1 * KD / 4;
    cvt_f32_bf16_kernel<<<(n4 + 255) / 256, 256, 0, stream>>>(wqkv, wqkvb, n4);
  }
  {
    int n4 = Dsz * KD / 4;
    cvt_f32_bf16_kernel<<<(n4 + 255) / 256, 256, 0, stream>>>(wo, wob, n4);
  }
  rope_tab_kernel<<<(Ssz * 32 + 255) / 256, 256, 0, stream>>>(pos, tab);

  gemm256_qkv_kernel<<<dim3(N1 / 256, Mrows / 256), 512, 0, stream>>>(
      xb, wqkvb, qbuf, kbuf, vtb, tab);

  attn_kernel<<<dim3(16 * 64), 256, 0, stream>>>(qbuf, kbuf, vtb, aout);

  gemm_out_kernel<<<dim3(Dsz / 128, Mrows / 128), 256, 0, stream>>>(
      aout, wob, KD, Dsz, out);
}

// Round 9
// 187.421 us; speedup vs baseline: 1.1127x; 1.1127x over previous
//
#include <hip/hip_runtime.h>
#include <hip/hip_bf16.h>
#include <math.h>

typedef __bf16 bf16_t;
typedef __attribute__((ext_vector_type(8))) __bf16 bf16x8;
typedef __attribute__((ext_vector_type(4))) __bf16 bf16x4;
typedef __attribute__((ext_vector_type(4))) float f32x4;

#define MFMA_16x16x32(A_, B_, C_) __builtin_amdgcn_mfma_f32_16x16x32_bf16((A_), (B_), (C_), 0, 0, 0)

#define Bsz 4
#define Ssz 2048
#define Dsz 1024
#define Hh 16
#define DKd 64
#define Mrows (Bsz * Ssz)  /* 8192 */
#define N1 (3 * Dsz)       /* 3072 */
#define KD Dsz             /* 1024 */

// ---------------- f32 -> bf16 conversion (x4 vectorized) ----------------
__global__ void cvt_f32_bf16_kernel(const float* __restrict__ src, bf16_t* __restrict__ dst, int n4) {
  int i = blockIdx.x * blockDim.x + threadIdx.x;
  if (i >= n4) return;
  float4 v = reinterpret_cast<const float4*>(src)[i];
  bf16x4 o = {(bf16_t)v.x, (bf16_t)v.y, (bf16_t)v.z, (bf16_t)v.w};
  reinterpret_cast<bf16x4*>(dst)[i] = o;
}

// ---------------- RoPE cos/sin table: [S][32] float2 ----------------
__global__ void rope_tab_kernel(const int* __restrict__ pos, float2* __restrict__ tab) {
  int i = blockIdx.x * blockDim.x + threadIdx.x;
  if (i >= Ssz * 32) return;
  int s = i >> 5, f = i & 31;
  float inv_freq = powf(10000.0f, -(float)(2 * f) / 64.0f);
  float a = (float)pos[s] * inv_freq;
  tab[i] = make_float2(cosf(a), sinf(a));
}

// ============ QKV GEMM: 256(M) x 192(N) tile, BK=64, 8 waves (2Mx4N) ============
// Grid (3072/192) x (8192/256) = 512 blocks = exactly 2 balanced rounds on 256
// CUs (fixes R7's 384-block 33% tail). R7-proven loop: stage whole next tile
// (7 x global_load_lds w=16) at tile top, 48 MFMA/wave, one __syncthreads.
// Swizzle: LDS chunk c of row r holds global chunk c ^ ((r>>1)&7); read side
// XOR (lr>>1) (rows 16-aligned) -> 0 bank conflicts (verified R7).
__global__ __launch_bounds__(512, 2) void gemm256_qkv_kernel(
    const bf16_t* __restrict__ A, const bf16_t* __restrict__ Bt,
    bf16_t* __restrict__ qb, bf16_t* __restrict__ kb, bf16_t* __restrict__ vtb,
    const float2* __restrict__ tab) {
  constexpr int NT = KD / 64;  // 16
  __shared__ __align__(16) bf16_t As[2][256 * 64];
  __shared__ __align__(16) bf16_t Bs[2][192 * 64];
  const int t = threadIdx.x;
  const int w = t >> 6, l = t & 63;
  const int lr = l & 15, lk = l >> 4;
  const int rs = lr >> 1;             // read-side swizzle (0..7)
  const int wm = w >> 2, wn = w & 3;  // 2M x 4N waves
  const int m0 = blockIdx.y * 256, n0 = blockIdx.x * 192;

  // staging: thread t -> row t>>3 within a 64-row issue, LDS chunk t&7 holding
  // global chunk (t&7)^((row>>1)&7) = (t&7)^((t>>4)&7) (issue base is 64-row
  // aligned so the XOR term is issue-invariant). LDS dest lane-linear.
  const int gcol = ((t & 7) ^ ((t >> 4) & 7)) * 8;
  const bf16_t* gA = A + (size_t)(m0 + (t >> 3)) * KD + gcol;
  const bf16_t* gB = Bt + (size_t)(n0 + (t >> 3)) * KD + gcol;

  f32x4 acc[8][3] = {};

#define QSTAGE(PH, KT)                                                                 \
  do {                                                                                 \
    _Pragma("unroll") for (int i = 0; i < 4; ++i)                                      \
        __builtin_amdgcn_global_load_lds(gA + (size_t)i * 64 * KD + (KT),              \
                                         &As[PH][(i * 64 + w * 8) * 64], 16, 0, 0);    \
    _Pragma("unroll") for (int i = 0; i < 3; ++i)                                      \
        __builtin_amdgcn_global_load_lds(gB + (size_t)i * 64 * KD + (KT),              \
                                         &Bs[PH][(i * 64 + w * 8) * 64], 16, 0, 0);    \
  } while (0)

  QSTAGE(0, 0);
  __syncthreads();
  for (int tt = 0; tt < NT; ++tt) {
    const int b = tt & 1;
    if (tt + 1 < NT) QSTAGE(b ^ 1, (tt + 1) * 64);
    bf16x8 bfv[3][2];
#pragma unroll
    for (int n = 0; n < 3; ++n) {
      const int R = wn * 48 + n * 16 + lr;
#pragma unroll
      for (int ks = 0; ks < 2; ++ks)
        bfv[n][ks] = *reinterpret_cast<const bf16x8*>(&Bs[b][R * 64 + (((ks * 4 + lk) ^ rs) * 8)]);
    }
#pragma unroll
    for (int mp = 0; mp < 4; ++mp) {
      bf16x8 af[2][2];
#pragma unroll
      for (int mi = 0; mi < 2; ++mi) {
        const int R = wm * 128 + (mp * 2 + mi) * 16 + lr;
#pragma unroll
        for (int ks = 0; ks < 2; ++ks)
          af[mi][ks] = *reinterpret_cast<const bf16x8*>(&As[b][R * 64 + (((ks * 4 + lk) ^ rs) * 8)]);
      }
      __builtin_amdgcn_s_setprio(1);
#pragma unroll
      for (int mi = 0; mi < 2; ++mi)
#pragma unroll
        for (int n = 0; n < 3; ++n) {
          acc[mp * 2 + mi][n] = MFMA_16x16x32(af[mi][0], bfv[n][0], acc[mp * 2 + mi][n]);
          acc[mp * 2 + mi][n] = MFMA_16x16x32(af[mi][1], bfv[n][1], acc[mp * 2 + mi][n]);
        }
      __builtin_amdgcn_s_setprio(0);
    }
    __syncthreads();
  }
#undef QSTAGE

  // ---- epilogue: per-n section decode (16-col groups never straddle 64/1024
  // boundaries, so sect/h are wave-uniform per n) ----
#pragma unroll
  for (int n = 0; n < 3; ++n) {
    const int colbase = n0 + wn * 48 + n * 16;
    const int sect = colbase >> 10;  // 0=q 1=k 2=v
    const int h = (colbase >> 6) & 15;
    const int dk = (colbase & 63) + lr;
    if (sect < 2) {
      bf16_t* dst0 = (sect == 0) ? qb : kb;
#pragma unroll
      for (int m = 0; m < 8; ++m)
#pragma unroll
        for (int r = 0; r < 4; ++r) {
          const int grow = m0 + wm * 128 + m * 16 + lk * 4 + r;
          const int bb = grow >> 11, s = grow & (Ssz - 1);
          const float v = acc[m][n][r];
          const float pv = __shfl_xor(v, 1);
          const float2 cs = tab[(s << 5) | (dk >> 1)];
          float vr = (dk & 1) ? (pv * cs.y + v * cs.x) : (v * cs.x - pv * cs.y);
          if (sect == 0) vr *= 0.125f;
          dst0[((size_t)(bb * Hh + h) * Ssz + s) * DKd + dk] = (bf16_t)vr;
        }
    } else {
#pragma unroll
      for (int m = 0; m < 8; ++m)
#pragma unroll
        for (int r = 0; r < 4; ++r) {
          const int grow = m0 + wm * 128 + m * 16 + lk * 4 + r;
          const int bb = grow >> 11, s = grow & (Ssz - 1);
          vtb[((size_t)(bb * Hh + h) * DKd + dk) * Ssz + s] = (bf16_t)acc[m][n][r];
        }
    }
  }
}

// ============ out-proj GEMM: 256(M) x 128(N) tile, BK=64, 8 waves ============
// Grid (1024/128) x (8192/256) = 256 blocks = exactly 1/CU (balanced).
__global__ __launch_bounds__(512, 2) void gemm_out_kernel(
    const bf16_t* __restrict__ A, const bf16_t* __restrict__ Bt,
    float* __restrict__ fout) {
  constexpr int NT = KD / 64;  // 16
  __shared__ __align__(16) bf16_t As[2][256 * 64];
  __shared__ __align__(16) bf16_t Bs[2][128 * 64];
  const int t = threadIdx.x;
  const int w = t >> 6, l = t & 63;
  const int lr = l & 15, lk = l >> 4;
  const int rs = lr >> 1;
  const int wm = w >> 2, wn = w & 3;
  const int m0 = blockIdx.y * 256, n0 = blockIdx.x * 128;

  const int gcol = ((t & 7) ^ ((t >> 4) & 7)) * 8;
  const bf16_t* gA = A + (size_t)(m0 + (t >> 3)) * KD + gcol;
  const bf16_t* gB = Bt + (size_t)(n0 + (t >> 3)) * KD + gcol;

  f32x4 acc[8][2] = {};

#define OSTAGE(PH, KT)                                                                 \
  do {                                                                                 \
    _Pragma("unroll") for (int i = 0; i < 4; ++i)                                      \
        __builtin_amdgcn_global_load_lds(gA + (size_t)i * 64 * KD + (KT),              \
                                         &As[PH][(i * 64 + w * 8) * 64], 16, 0, 0);    \
    _Pragma("unroll") for (int i = 0; i < 2; ++i)                                      \
        __builtin_amdgcn_global_load_lds(gB + (size_t)i * 64 * KD + (KT),              \
                                         &Bs[PH][(i * 64 + w * 8) * 64], 16, 0, 0);    \
  } while (0)

  OSTAGE(0, 0);
  __syncthreads();
  for (int tt = 0; tt < NT; ++tt) {
    const int b = tt & 1;
    if (tt + 1 < NT) OSTAGE(b ^ 1, (tt + 1) * 64);
    bf16x8 bfv[2][2];
#pragma unroll
    for (int n = 0; n < 2; ++n) {
      const int R = wn * 32 + n * 16 + lr;
#pragma unroll
      for (int ks = 0; ks < 2; ++ks)
        bfv[n][ks] = *reinterpret_cast<const bf16x8*>(&Bs[b][R * 64 + (((ks * 4 + lk) ^ rs) * 8)]);
    }
#pragma unroll
    for (int mp = 0; mp < 4; ++mp) {
      bf16x8 af[2][2];
#pragma unroll
      for (int mi = 0; mi < 2; ++mi) {
        const int R = wm * 128 + (mp * 2 + mi) * 16 + lr;
#pragma unroll
        for (int ks = 0; ks < 2; ++ks)
          af[mi][ks] = *reinterpret_cast<const bf16x8*>(&As[b][R * 64 + (((ks * 4 + lk) ^ rs) * 8)]);
      }
      __builtin_amdgcn_s_setprio(1);
#pragma unroll
      for (int mi = 0; mi < 2; ++mi)
#pragma unroll
        for (int n = 0; n < 2; ++n) {
          acc[mp * 2 + mi][n] = MFMA_16x16x32(af[mi][0], bfv[n][0], acc[mp * 2 + mi][n]);
          acc[mp * 2 + mi][n] = MFMA_16x16x32(af[mi][1], bfv[n][1], acc[mp * 2 + mi][n]);
        }
      __builtin_amdgcn_s_setprio(0);
    }
    __syncthreads();
  }
#undef OSTAGE

#pragma unroll
  for (int m = 0; m < 8; ++m)
#pragma unroll
    for (int r = 0; r < 4; ++r) {
      const int grow = m0 + wm * 128 + m * 16 + lk * 4 + r;
      float* op = fout + (size_t)grow * Dsz + n0 + wn * 32 + lr;
      op[0] = acc[m][0][r];
      op[16] = acc[m][1][r];
    }
}

// ---------------- causal flash attention, swapped-QK^T / in-lane softmax ----
__global__ __launch_bounds__(256, 3) void attn_kernel(
    const bf16_t* __restrict__ qb, const bf16_t* __restrict__ kb,
    const bf16_t* __restrict__ vtb, bf16_t* __restrict__ aout) {
  __shared__ __align__(16) bf16_t Ks[64 * 64];
  __shared__ __align__(16) bf16_t Vs[64 * 64];
  const int t = threadIdx.x, w = t >> 6, l = t & 63;
  const int lr = l & 15, lk = l >> 4;
  const int bid = blockIdx.x;
  const int bh = (bid & 7) * 8 + ((bid >> 3) & 7);
  const int qt = 15 - (bid >> 6);  // heavy-first
  const int q0 = qt * 128;
  const int sub0 = q0 + w * 32;

  const bf16_t* qbase = qb + ((size_t)bh * Ssz + sub0) * DKd;
  bf16x8 qf[2][2];
#pragma unroll
  for (int s = 0; s < 2; ++s) {
    qf[s][0] = *reinterpret_cast<const bf16x8*>(qbase + (s * 16 + lr) * DKd + lk * 8);
    qf[s][1] = *reinterpret_cast<const bf16x8*>(qbase + (s * 16 + lr) * DKd + 32 + lk * 8);
  }

  f32x4 o[2][4] = {};
  float mrow[2] = {-INFINITY, -INFINITY};
  float lsum[2] = {0.f, 0.f};

  const int srow = t >> 2;
  const int scc = (t & 3) * 2;
  const bf16_t* kg = kb + ((size_t)bh * Ssz + srow) * DKd + scc * 8;
  const bf16_t* vg = vtb + ((size_t)bh * DKd + srow) * Ssz + scc * 8;
  bf16_t* ksw0 = Ks + srow * 64 + ((scc ^ (srow & 7)) * 8);
  bf16_t* ksw1 = Ks + srow * 64 + (((scc + 1) ^ (srow & 7)) * 8);
  bf16_t* vw[4];
#pragma unroll
  for (int u = 0; u < 2; ++u) {
    const int c = scc + u;
    const int B = 32 * (c >> 2) + 16 * (c & 1) + 4 * ((c & 3) >> 1);
    const int ch = B >> 3, off = B & 7;
    vw[2 * u] = Vs + srow * 64 + ((ch ^ (srow & 7)) * 8) + off;
    vw[2 * u + 1] = Vs + srow * 64 + (((ch + 1) ^ (srow & 7)) * 8) + off;
  }

  const int kvend = q0 + 128;
  bf16x8 pk0 = *reinterpret_cast<const bf16x8*>(kg);
  bf16x8 pk1 = *reinterpret_cast<const bf16x8*>(kg + 8);
  bf16x8 pv0 = *reinterpret_cast<const bf16x8*>(vg);
  bf16x8 pv1 = *reinterpret_cast<const bf16x8*>(vg + 8);

  for (int kv = 0; kv < kvend; kv += 64) {
    __syncthreads();
    *reinterpret_cast<bf16x8*>(ksw0) = pk0;
    *reinterpret_cast<bf16x8*>(ksw1) = pk1;
    *reinterpret_cast<bf16x4*>(vw[0]) = __builtin_shufflevector(pv0, pv0, 0, 1, 2, 3);
    *reinterpret_cast<bf16x4*>(vw[1]) = __builtin_shufflevector(pv0, pv0, 4, 5, 6, 7);
    *reinterpret_cast<bf16x4*>(vw[2]) = __builtin_shufflevector(pv1, pv1, 0, 1, 2, 3);
    *reinterpret_cast<bf16x4*>(vw[3]) = __builtin_shufflevector(pv1, pv1, 4, 5, 6, 7);
    __syncthreads();
    if (kv + 64 < kvend) {
      pk0 = *reinterpret_cast<const bf16x8*>(kg + (size_t)(kv + 64) * DKd);
      pk1 = *reinterpret_cast<const bf16x8*>(kg + (size_t)(kv + 64) * DKd + 8);
      pv0 = *reinterpret_cast<const bf16x8*>(vg + kv + 64);
      pv1 = *reinterpret_cast<const bf16x8*>(vg + kv + 64 + 8);
    }
#pragma unroll
    for (int s = 0; s < 2; ++s) {
      const int subrow = sub0 + s * 16;
      if (kv > subrow + 15) continue;
      f32x4 sa[4];
#pragma unroll
      for (int n = 0; n < 4; ++n) {
        const int R = n * 16 + lr;
        const bf16x8 a0 = *reinterpret_cast<const bf16x8*>(Ks + R * 64 + ((lk ^ (R & 7)) * 8));
        const bf16x8 a1 = *reinterpret_cast<const bf16x8*>(Ks + R * 64 + (((lk + 4) ^ (R & 7)) * 8));
        f32x4 z = {};
        z = MFMA_16x16x32(a0, qf[s][0], z);
        z = MFMA_16x16x32(a1, qf[s][1], z);
        sa[n] = z;
      }
      if (kv + 63 > subrow) {
        const int qrow = subrow + lr;
        const int kbase = kv + lk * 4;
#pragma unroll
        for (int n = 0; n < 4; ++n)
#pragma unroll
          for (int r = 0; r < 4; ++r)
            if (kbase + n * 16 + r > qrow) sa[n][r] = -INFINITY;
      }
      float mx = fmaxf(fmaxf(fmaxf(sa[0][0], sa[0][1]), fmaxf(sa[0][2], sa[0][3])),
                       fmaxf(fmaxf(sa[1][0], sa[1][1]), fmaxf(sa[1][2], sa[1][3])));
      mx = fmaxf(mx, fmaxf(fmaxf(fmaxf(sa[2][0], sa[2][1]), fmaxf(sa[2][2], sa[2][3])),
                           fmaxf(fmaxf(sa[3][0], sa[3][1]), fmaxf(sa[3][2], sa[3][3]))));
      mx = fmaxf(mx, __shfl_xor(mx, 16));
      mx = fmaxf(mx, __shfl_xor(mx, 32));
      const float mnew = fmaxf(mrow[s], mx);
      const float scl = __expf(mrow[s] - mnew);
      mrow[s] = mnew;
      float ps = 0.f;
#pragma unroll
      for (int n = 0; n < 4; ++n)
#pragma unroll
        for (int r = 0; r < 4; ++r) {
          const float p = __expf(sa[n][r] - mnew);
          sa[n][r] = p;
          ps += p;
        }
      lsum[s] = lsum[s] * scl + ps;
#pragma unroll
      for (int n = 0; n < 4; ++n)
#pragma unroll
        for (int r = 0; r < 4; ++r) o[s][n][r] *= scl;
      bf16x8 pb0, pb1;
#pragma unroll
      for (int r = 0; r < 4; ++r) {
        pb0[r] = (bf16_t)sa[0][r];
        pb0[4 + r] = (bf16_t)sa[1][r];
        pb1[r] = (bf16_t)sa[2][r];
        pb1[4 + r] = (bf16_t)sa[3][r];
      }
#pragma unroll
      for (int n = 0; n < 4; ++n) {
        const int R = n * 16 + lr;
        const bf16x8 v0 = *reinterpret_cast<const bf16x8*>(Vs + R * 64 + ((lk ^ (R & 7)) * 8));
        const bf16x8 v1 = *reinterpret_cast<const bf16x8*>(Vs + R * 64 + (((lk + 4) ^ (R & 7)) * 8));
        o[s][n] = MFMA_16x16x32(v0, pb0, o[s][n]);
        o[s][n] = MFMA_16x16x32(v1, pb1, o[s][n]);
      }
    }
  }
  const int b_ = bh >> 4, h_ = bh & 15;
#pragma unroll
  for (int s = 0; s < 2; ++s) {
    float sm = lsum[s];
    sm += __shfl_xor(sm, 16);
    sm += __shfl_xor(sm, 32);
    const float inv = 1.0f / sm;
    const int qrow = sub0 + s * 16 + lr;
    bf16_t* op = aout + ((size_t)b_ * Ssz + qrow) * Dsz + h_ * DKd + lk * 4;
#pragma unroll
    for (int n = 0; n < 4; ++n) {
      const bf16x4 ov = {(bf16_t)(o[s][n][0] * inv), (bf16_t)(o[s][n][1] * inv),
                         (bf16_t)(o[s][n][2] * inv), (bf16_t)(o[s][n][3] * inv)};
      *reinterpret_cast<bf16x4*>(op + n * 16) = ov;
    }
  }
}

extern "C" void kernel_launch(void* const* d_in, const int* in_sizes, int n_in,
                              void* d_out, int out_size, void* d_ws, size_t ws_size,
                              hipStream_t stream) {
  const float* x = (const float*)d_in[0];
  const int* pos = (const int*)d_in[1];
  const float* wqkv = (const float*)d_in[2];
  const float* wo = (const float*)d_in[3];
  float* out = (float*)d_out;

  bf16_t* xb = (bf16_t*)d_ws;
  bf16_t* wqkvb = xb + (size_t)Mrows * KD;
  bf16_t* wob = wqkvb + (size_t)N1 * KD;
  bf16_t* qbuf = wob + (size_t)Dsz * KD;
  bf16_t* kbuf = qbuf + (size_t)64 * Ssz * DKd;
  bf16_t* vtb = kbuf + (size_t)64 * Ssz * DKd;
  float2* tab = (float2*)(vtb + (size_t)64 * Ssz * DKd);
  bf16_t* aout = xb;

  {
    int n4 = Mrows * KD / 4;
    cvt_f32_bf16_kernel<<<(n4 + 255) / 256, 256, 0, stream>>>(x, xb, n4);
  }
  {
    int n4 = N1 * KD / 4;
    cvt_f32_bf16_kernel<<<(n4 + 255) / 256, 256, 0, stream>>>(wqkv, wqkvb, n4);
  }
  {
    int n4 = Dsz * KD / 4;
    cvt_f32_bf16_kernel<<<(n4 + 255) / 256, 256, 0, stream>>>(wo, wob, n4);
  }
  rope_tab_kernel<<<(Ssz * 32 + 255) / 256, 256, 0, stream>>>(pos, tab);

  gemm256_qkv_kernel<<<dim3(N1 / 192, Mrows / 256), 512, 0, stream>>>(
      xb, wqkvb, qbuf, kbuf, vtb, tab);

  attn_kernel<<<dim3(16 * 64), 256, 0, stream>>>(qbuf, kbuf, vtb, aout);

  gemm_out_kernel<<<dim3(Dsz / 128, Mrows / 256), 512, 0, stream>>>(
      aout, wob, out);
}

// Round 10
// 178.986 us; speedup vs baseline: 1.1652x; 1.0471x over previous
//
#include <hip/hip_runtime.h>
#include <hip/hip_bf16.h>
#include <math.h>

typedef __bf16 bf16_t;
typedef __attribute__((ext_vector_type(8))) __bf16 bf16x8;
typedef __attribute__((ext_vector_type(4))) __bf16 bf16x4;
typedef __attribute__((ext_vector_type(4))) float f32x4;

#define MFMA_16x16x32(A_, B_, C_) __builtin_amdgcn_mfma_f32_16x16x32_bf16((A_), (B_), (C_), 0, 0, 0)

#define Bsz 4
#define Ssz 2048
#define Dsz 1024
#define Hh 16
#define DKd 64
#define Mrows (Bsz * Ssz)  /* 8192 */
#define N1 (3 * Dsz)       /* 3072 */
#define KD Dsz             /* 1024 */

// ---------------- f32 -> bf16 conversion (x4 vectorized) ----------------
__global__ void cvt_f32_bf16_kernel(const float* __restrict__ src, bf16_t* __restrict__ dst, int n4) {
  int i = blockIdx.x * blockDim.x + threadIdx.x;
  if (i >= n4) return;
  float4 v = reinterpret_cast<const float4*>(src)[i];
  bf16x4 o = {(bf16_t)v.x, (bf16_t)v.y, (bf16_t)v.z, (bf16_t)v.w};
  reinterpret_cast<bf16x4*>(dst)[i] = o;
}

// ---------------- RoPE cos/sin table: [S][32] float2 ----------------
__global__ void rope_tab_kernel(const int* __restrict__ pos, float2* __restrict__ tab) {
  int i = blockIdx.x * blockDim.x + threadIdx.x;
  if (i >= Ssz * 32) return;
  int s = i >> 5, f = i & 31;
  float inv_freq = powf(10000.0f, -(float)(2 * f) / 64.0f);
  float a = (float)pos[s] * inv_freq;
  tab[i] = make_float2(cosf(a), sinf(a));
}

// ============ QKV GEMM: 256(M) x 192(N), BK=64, 8 waves, 8-PHASE schedule ====
// Per K-tile: 4 phases x 12 MFMA (m-quadrant x 3n x 2ks). Phase = {ds_read
// quadrant ; issue 2 gload_lds for t+1} -> barrier -> lgkm(0) -> MFMA ->
// [counted vmcnt] -> barrier. Stage order B0,B1|B2,A0|A2,A1|A3; waits
// vmcnt(4)@end-ph1 (lands A1,A3), vmcnt(2)@end-ph3 (lands B*,A0,A2) -- never
// 0 in the loop (T4). Last tile stages kt=0 into the dead buffer to keep
// counts uniform. Swizzle as R9 (verified 0 conflicts).
__global__ __launch_bounds__(512, 1) void gemm256_qkv_kernel(
    const bf16_t* __restrict__ A, const bf16_t* __restrict__ Bt,
    bf16_t* __restrict__ qb, bf16_t* __restrict__ kb, bf16_t* __restrict__ vtb,
    const float2* __restrict__ tab) {
  constexpr int NT = KD / 64;  // 16
  __shared__ __align__(16) bf16_t As[2][256 * 64];
  __shared__ __align__(16) bf16_t Bs[2][192 * 64];
  const int t = threadIdx.x;
  const int w = t >> 6, l = t & 63;
  const int lr = l & 15, lk = l >> 4;
  const int rs = lr >> 1;             // read-side swizzle (0..7)
  const int wm = w >> 2, wn = w & 3;  // 2M x 4N waves
  const int m0 = blockIdx.y * 256, n0 = blockIdx.x * 192;

  const int gcol = ((t & 7) ^ ((t >> 4) & 7)) * 8;
  const bf16_t* gA = A + (size_t)(m0 + (t >> 3)) * KD + gcol;
  const bf16_t* gB = Bt + (size_t)(n0 + (t >> 3)) * KD + gcol;

  f32x4 acc[8][3] = {};
  bf16x8 bfv[3][2];

#define LDA_(I_, SB_, KT_)                                                        \
  __builtin_amdgcn_global_load_lds(gA + (size_t)(I_) * 64 * KD + (KT_),           \
                                   &As[SB_][((I_) * 64 + w * 8) * 64], 16, 0, 0)
#define LDB_(I_, SB_, KT_)                                                        \
  __builtin_amdgcn_global_load_lds(gB + (size_t)(I_) * 64 * KD + (KT_),           \
                                   &Bs[SB_][((I_) * 64 + w * 8) * 64], 16, 0, 0)

#define PH(BUF_, P_, STG0_, STG1_, VMW_)                                          \
  do {                                                                            \
    if ((P_) == 0) {                                                              \
      _Pragma("unroll") for (int n_ = 0; n_ < 3; ++n_) {                          \
        const int R_ = wn * 48 + n_ * 16 + lr;                                    \
        bfv[n_][0] = *reinterpret_cast<const bf16x8*>(                            \
            &Bs[BUF_][R_ * 64 + ((lk ^ rs) * 8)]);                                \
        bfv[n_][1] = *reinterpret_cast<const bf16x8*>(                            \
            &Bs[BUF_][R_ * 64 + (((4 + lk) ^ rs) * 8)]);                          \
      }                                                                           \
    }                                                                             \
    bf16x8 af0_[2], af1_[2];                                                      \
    {                                                                             \
      const int Ra_ = wm * 128 + (P_) * 32 + lr;                                  \
      const int Rb_ = Ra_ + 16;                                                   \
      af0_[0] = *reinterpret_cast<const bf16x8*>(&As[BUF_][Ra_ * 64 + ((lk ^ rs) * 8)]);       \
      af0_[1] = *reinterpret_cast<const bf16x8*>(&As[BUF_][Ra_ * 64 + (((4 + lk) ^ rs) * 8)]); \
      af1_[0] = *reinterpret_cast<const bf16x8*>(&As[BUF_][Rb_ * 64 + ((lk ^ rs) * 8)]);       \
      af1_[1] = *reinterpret_cast<const bf16x8*>(&As[BUF_][Rb_ * 64 + (((4 + lk) ^ rs) * 8)]); \
    }                                                                             \
    STG0_;                                                                        \
    STG1_;                                                                        \
    __builtin_amdgcn_s_barrier();                                                 \
    asm volatile("s_waitcnt lgkmcnt(0)" ::: "memory");                            \
    __builtin_amdgcn_sched_barrier(0);                                            \
    __builtin_amdgcn_s_setprio(1);                                                \
    _Pragma("unroll") for (int n_ = 0; n_ < 3; ++n_) {                            \
      acc[(P_)*2][n_] = MFMA_16x16x32(af0_[0], bfv[n_][0], acc[(P_)*2][n_]);      \
      acc[(P_)*2][n_] = MFMA_16x16x32(af0_[1], bfv[n_][1], acc[(P_)*2][n_]);      \
      acc[(P_)*2 + 1][n_] = MFMA_16x16x32(af1_[0], bfv[n_][0], acc[(P_)*2 + 1][n_]); \
      acc[(P_)*2 + 1][n_] = MFMA_16x16x32(af1_[1], bfv[n_][1], acc[(P_)*2 + 1][n_]); \
    }                                                                             \
    __builtin_amdgcn_s_setprio(0);                                                \
    VMW_;                                                                         \
    __builtin_amdgcn_s_barrier();                                                 \
  } while (0)

#define VM4_ do { asm volatile("s_waitcnt vmcnt(4)" ::: "memory"); __builtin_amdgcn_sched_barrier(0); } while (0)
#define VM2_ do { asm volatile("s_waitcnt vmcnt(2)" ::: "memory"); __builtin_amdgcn_sched_barrier(0); } while (0)

#define TILE_(BUF_, KTN_)                                                         \
  do {                                                                            \
    PH(BUF_, 0, LDB_(0, (BUF_) ^ 1, KTN_), LDB_(1, (BUF_) ^ 1, KTN_), (void)0);   \
    PH(BUF_, 1, LDB_(2, (BUF_) ^ 1, KTN_), LDA_(0, (BUF_) ^ 1, KTN_), VM4_);      \
    PH(BUF_, 2, LDA_(2, (BUF_) ^ 1, KTN_), LDA_(1, (BUF_) ^ 1, KTN_), (void)0);   \
    PH(BUF_, 3, LDA_(3, (BUF_) ^ 1, KTN_), (void)0, VM2_);                        \
  } while (0)

  // prologue: stage tile 0 in the vmcnt-schedule order, land first 5, barrier
  LDB_(0, 0, 0); LDB_(1, 0, 0); LDB_(2, 0, 0);
  LDA_(0, 0, 0); LDA_(2, 0, 0); LDA_(1, 0, 0); LDA_(3, 0, 0);
  asm volatile("s_waitcnt vmcnt(2)" ::: "memory");
  __builtin_amdgcn_s_barrier();

#pragma unroll 1
  for (int tt = 0; tt < NT; tt += 2) {
    const int ktn0 = ((tt + 1) & (NT - 1)) * 64;  // last tile wraps to 0 (dead buf)
    TILE_(0, ktn0);
    const int ktn1 = ((tt + 2) & (NT - 1)) * 64;
    TILE_(1, ktn1);
  }
#undef TILE_
#undef VM4_
#undef VM2_
#undef PH
#undef LDA_
#undef LDB_

  // ---- epilogue: per-n section decode ----
#pragma unroll
  for (int n = 0; n < 3; ++n) {
    const int colbase = n0 + wn * 48 + n * 16;
    const int sect = colbase >> 10;  // 0=q 1=k 2=v
    const int h = (colbase >> 6) & 15;
    const int dk = (colbase & 63) + lr;
    if (sect < 2) {
      bf16_t* dst0 = (sect == 0) ? qb : kb;
#pragma unroll
      for (int m = 0; m < 8; ++m)
#pragma unroll
        for (int r = 0; r < 4; ++r) {
          const int grow = m0 + wm * 128 + m * 16 + lk * 4 + r;
          const int bb = grow >> 11, s = grow & (Ssz - 1);
          const float v = acc[m][n][r];
          const float pv = __shfl_xor(v, 1);
          const float2 cs = tab[(s << 5) | (dk >> 1)];
          float vr = (dk & 1) ? (pv * cs.y + v * cs.x) : (v * cs.x - pv * cs.y);
          if (sect == 0) vr *= 0.125f;
          dst0[((size_t)(bb * Hh + h) * Ssz + s) * DKd + dk] = (bf16_t)vr;
        }
    } else {
#pragma unroll
      for (int m = 0; m < 8; ++m) {
        const int grow0 = m0 + wm * 128 + m * 16 + lk * 4;
        const int bb = grow0 >> 11, s0 = grow0 & (Ssz - 1);
        const bf16x4 ov = {(bf16_t)acc[m][n][0], (bf16_t)acc[m][n][1],
                           (bf16_t)acc[m][n][2], (bf16_t)acc[m][n][3]};
        *reinterpret_cast<bf16x4*>(
            vtb + ((size_t)(bb * Hh + h) * DKd + dk) * Ssz + s0) = ov;
      }
    }
  }
}

// ============ out-proj GEMM: 256(M) x 128(N) tile, BK=64, 8 waves ============
__global__ __launch_bounds__(512, 2) void gemm_out_kernel(
    const bf16_t* __restrict__ A, const bf16_t* __restrict__ Bt,
    float* __restrict__ fout) {
  constexpr int NT = KD / 64;  // 16
  __shared__ __align__(16) bf16_t As[2][256 * 64];
  __shared__ __align__(16) bf16_t Bs[2][128 * 64];
  const int t = threadIdx.x;
  const int w = t >> 6, l = t & 63;
  const int lr = l & 15, lk = l >> 4;
  const int rs = lr >> 1;
  const int wm = w >> 2, wn = w & 3;
  const int m0 = blockIdx.y * 256, n0 = blockIdx.x * 128;

  const int gcol = ((t & 7) ^ ((t >> 4) & 7)) * 8;
  const bf16_t* gA = A + (size_t)(m0 + (t >> 3)) * KD + gcol;
  const bf16_t* gB = Bt + (size_t)(n0 + (t >> 3)) * KD + gcol;

  f32x4 acc[8][2] = {};

#define OSTAGE(PH, KT)                                                                 \
  do {                                                                                 \
    _Pragma("unroll") for (int i = 0; i < 4; ++i)                                      \
        __builtin_amdgcn_global_load_lds(gA + (size_t)i * 64 * KD + (KT),              \
                                         &As[PH][(i * 64 + w * 8) * 64], 16, 0, 0);    \
    _Pragma("unroll") for (int i = 0; i < 2; ++i)                                      \
        __builtin_amdgcn_global_load_lds(gB + (size_t)i * 64 * KD + (KT),              \
                                         &Bs[PH][(i * 64 + w * 8) * 64], 16, 0, 0);    \
  } while (0)

  OSTAGE(0, 0);
  __syncthreads();
  for (int tt = 0; tt < NT; ++tt) {
    const int b = tt & 1;
    if (tt + 1 < NT) OSTAGE(b ^ 1, (tt + 1) * 64);
    bf16x8 bfv[2][2];
#pragma unroll
    for (int n = 0; n < 2; ++n) {
      const int R = wn * 32 + n * 16 + lr;
#pragma unroll
      for (int ks = 0; ks < 2; ++ks)
        bfv[n][ks] = *reinterpret_cast<const bf16x8*>(&Bs[b][R * 64 + (((ks * 4 + lk) ^ rs) * 8)]);
    }
#pragma unroll
    for (int mp = 0; mp < 4; ++mp) {
      bf16x8 af[2][2];
#pragma unroll
      for (int mi = 0; mi < 2; ++mi) {
        const int R = wm * 128 + (mp * 2 + mi) * 16 + lr;
#pragma unroll
        for (int ks = 0; ks < 2; ++ks)
          af[mi][ks] = *reinterpret_cast<const bf16x8*>(&As[b][R * 64 + (((ks * 4 + lk) ^ rs) * 8)]);
      }
      __builtin_amdgcn_s_setprio(1);
#pragma unroll
      for (int mi = 0; mi < 2; ++mi)
#pragma unroll
        for (int n = 0; n < 2; ++n) {
          acc[mp * 2 + mi][n] = MFMA_16x16x32(af[mi][0], bfv[n][0], acc[mp * 2 + mi][n]);
          acc[mp * 2 + mi][n] = MFMA_16x16x32(af[mi][1], bfv[n][1], acc[mp * 2 + mi][n]);
        }
      __builtin_amdgcn_s_setprio(0);
    }
    __syncthreads();
  }
#undef OSTAGE

#pragma unroll
  for (int m = 0; m < 8; ++m)
#pragma unroll
    for (int r = 0; r < 4; ++r) {
      const int grow = m0 + wm * 128 + m * 16 + lk * 4 + r;
      float* op = fout + (size_t)grow * Dsz + n0 + wn * 32 + lr;
      op[0] = acc[m][0][r];
      op[16] = acc[m][1][r];
    }
}

// ---------------- causal flash attention, swapped-QK^T / in-lane softmax ----
__global__ __launch_bounds__(256, 3) void attn_kernel(
    const bf16_t* __restrict__ qb, const bf16_t* __restrict__ kb,
    const bf16_t* __restrict__ vtb, bf16_t* __restrict__ aout) {
  __shared__ __align__(16) bf16_t Ks[64 * 64];
  __shared__ __align__(16) bf16_t Vs[64 * 64];
  const int t = threadIdx.x, w = t >> 6, l = t & 63;
  const int lr = l & 15, lk = l >> 4;
  const int bid = blockIdx.x;
  const int bh = (bid & 7) * 8 + ((bid >> 3) & 7);
  const int qt = 15 - (bid >> 6);  // heavy-first
  const int q0 = qt * 128;
  const int sub0 = q0 + w * 32;

  const bf16_t* qbase = qb + ((size_t)bh * Ssz + sub0) * DKd;
  bf16x8 qf[2][2];
#pragma unroll
  for (int s = 0; s < 2; ++s) {
    qf[s][0] = *reinterpret_cast<const bf16x8*>(qbase + (s * 16 + lr) * DKd + lk * 8);
    qf[s][1] = *reinterpret_cast<const bf16x8*>(qbase + (s * 16 + lr) * DKd + 32 + lk * 8);
  }

  f32x4 o[2][4] = {};
  float mrow[2] = {-INFINITY, -INFINITY};
  float lsum[2] = {0.f, 0.f};

  const int srow = t >> 2;
  const int scc = (t & 3) * 2;
  const bf16_t* kg = kb + ((size_t)bh * Ssz + srow) * DKd + scc * 8;
  const bf16_t* vg = vtb + ((size_t)bh * DKd + srow) * Ssz + scc * 8;
  bf16_t* ksw0 = Ks + srow * 64 + ((scc ^ (srow & 7)) * 8);
  bf16_t* ksw1 = Ks + srow * 64 + (((scc + 1) ^ (srow & 7)) * 8);
  bf16_t* vw[4];
#pragma unroll
  for (int u = 0; u < 2; ++u) {
    const int c = scc + u;
    const int B = 32 * (c >> 2) + 16 * (c & 1) + 4 * ((c & 3) >> 1);
    const int ch = B >> 3, off = B & 7;
    vw[2 * u] = Vs + srow * 64 + ((ch ^ (srow & 7)) * 8) + off;
    vw[2 * u + 1] = Vs + srow * 64 + (((ch + 1) ^ (srow & 7)) * 8) + off;
  }

  const int kvend = q0 + 128;
  bf16x8 pk0 = *reinterpret_cast<const bf16x8*>(kg);
  bf16x8 pk1 = *reinterpret_cast<const bf16x8*>(kg + 8);
  bf16x8 pv0 = *reinterpret_cast<const bf16x8*>(vg);
  bf16x8 pv1 = *reinterpret_cast<const bf16x8*>(vg + 8);

  for (int kv = 0; kv < kvend; kv += 64) {
    __syncthreads();
    *reinterpret_cast<bf16x8*>(ksw0) = pk0;
    *reinterpret_cast<bf16x8*>(ksw1) = pk1;
    *reinterpret_cast<bf16x4*>(vw[0]) = __builtin_shufflevector(pv0, pv0, 0, 1, 2, 3);
    *reinterpret_cast<bf16x4*>(vw[1]) = __builtin_shufflevector(pv0, pv0, 4, 5, 6, 7);
    *reinterpret_cast<bf16x4*>(vw[2]) = __builtin_shufflevector(pv1, pv1, 0, 1, 2, 3);
    *reinterpret_cast<bf16x4*>(vw[3]) = __builtin_shufflevector(pv1, pv1, 4, 5, 6, 7);
    __syncthreads();
    if (kv + 64 < kvend) {
      pk0 = *reinterpret_cast<const bf16x8*>(kg + (size_t)(kv + 64) * DKd);
      pk1 = *reinterpret_cast<const bf16x8*>(kg + (size_t)(kv + 64) * DKd + 8);
      pv0 = *reinterpret_cast<const bf16x8*>(vg + kv + 64);
      pv1 = *reinterpret_cast<const bf16x8*>(vg + kv + 64 + 8);
    }
#pragma unroll
    for (int s = 0; s < 2; ++s) {
      const int subrow = sub0 + s * 16;
      if (kv > subrow + 15) continue;
      f32x4 sa[4];
#pragma unroll
      for (int n = 0; n < 4; ++n) {
        const int R = n * 16 + lr;
        const bf16x8 a0 = *reinterpret_cast<const bf16x8*>(Ks + R * 64 + ((lk ^ (R & 7)) * 8));
        const bf16x8 a1 = *reinterpret_cast<const bf16x8*>(Ks + R * 64 + (((lk + 4) ^ (R & 7)) * 8));
        f32x4 z = {};
        z = MFMA_16x16x32(a0, qf[s][0], z);
        z = MFMA_16x16x32(a1, qf[s][1], z);
        sa[n] = z;
      }
      if (kv + 63 > subrow) {
        const int qrow = subrow + lr;
        const int kbase = kv + lk * 4;
#pragma unroll
        for (int n = 0; n < 4; ++n)
#pragma unroll
          for (int r = 0; r < 4; ++r)
            if (kbase + n * 16 + r > qrow) sa[n][r] = -INFINITY;
      }
      float mx = fmaxf(fmaxf(fmaxf(sa[0][0], sa[0][1]), fmaxf(sa[0][2], sa[0][3])),
                       fmaxf(fmaxf(sa[1][0], sa[1][1]), fmaxf(sa[1][2], sa[1][3])));
      mx = fmaxf(mx, fmaxf(fmaxf(fmaxf(sa[2][0], sa[2][1]), fmaxf(sa[2][2], sa[2][3])),
                           fmaxf(fmaxf(sa[3][0], sa[3][1]), fmaxf(sa[3][2], sa[3][3]))));
      mx = fmaxf(mx, __shfl_xor(mx, 16));
      mx = fmaxf(mx, __shfl_xor(mx, 32));
      const float mnew = fmaxf(mrow[s], mx);
      const float scl = __expf(mrow[s] - mnew);
      mrow[s] = mnew;
      float ps = 0.f;
#pragma unroll
      for (int n = 0; n < 4; ++n)
#pragma unroll
        for (int r = 0; r < 4; ++r) {
          const float p = __expf(sa[n][r] - mnew);
          sa[n][r] = p;
          ps += p;
        }
      lsum[s] = lsum[s] * scl + ps;
#pragma unroll
      for (int n = 0; n < 4; ++n)
#pragma unroll
        for (int r = 0; r < 4; ++r) o[s][n][r] *= scl;
      bf16x8 pb0, pb1;
#pragma unroll
      for (int r = 0; r < 4; ++r) {
        pb0[r] = (bf16_t)sa[0][r];
        pb0[4 + r] = (bf16_t)sa[1][r];
        pb1[r] = (bf16_t)sa[2][r];
        pb1[4 + r] = (bf16_t)sa[3][r];
      }
#pragma unroll
      for (int n = 0; n < 4; ++n) {
        const int R = n * 16 + lr;
        const bf16x8 v0 = *reinterpret_cast<const bf16x8*>(Vs + R * 64 + ((lk ^ (R & 7)) * 8));
        const bf16x8 v1 = *reinterpret_cast<const bf16x8*>(Vs + R * 64 + (((lk + 4) ^ (R & 7)) * 8));
        o[s][n] = MFMA_16x16x32(v0, pb0, o[s][n]);
        o[s][n] = MFMA_16x16x32(v1, pb1, o[s][n]);
      }
    }
  }
  const int b_ = bh >> 4, h_ = bh & 15;
#pragma unroll
  for (int s = 0; s < 2; ++s) {
    float sm = lsum[s];
    sm += __shfl_xor(sm, 16);
    sm += __shfl_xor(sm, 32);
    const float inv = 1.0f / sm;
    const int qrow = sub0 + s * 16 + lr;
    bf16_t* op = aout + ((size_t)b_ * Ssz + qrow) * Dsz + h_ * DKd + lk * 4;
#pragma unroll
    for (int n = 0; n < 4; ++n) {
      const bf16x4 ov = {(bf16_t)(o[s][n][0] * inv), (bf16_t)(o[s][n][1] * inv),
                         (bf16_t)(o[s][n][2] * inv), (bf16_t)(o[s][n][3] * inv)};
      *reinterpret_cast<bf16x4*>(op + n * 16) = ov;
    }
  }
}

extern "C" void kernel_launch(void* const* d_in, const int* in_sizes, int n_in,
                              void* d_out, int out_size, void* d_ws, size_t ws_size,
                              hipStream_t stream) {
  const float* x = (const float*)d_in[0];
  const int* pos = (const int*)d_in[1];
  const float* wqkv = (const float*)d_in[2];
  const float* wo = (const float*)d_in[3];
  float* out = (float*)d_out;

  bf16_t* xb = (bf16_t*)d_ws;
  bf16_t* wqkvb = xb + (size_t)Mrows * KD;
  bf16_t* wob = wqkvb + (size_t)N1 * KD;
  bf16_t* qbuf = wob + (size_t)Dsz * KD;
  bf16_t* kbuf = qbuf + (size_t)64 * Ssz * DKd;
  bf16_t* vtb = kbuf + (size_t)64 * Ssz * DKd;
  float2* tab = (float2*)(vtb + (size_t)64 * Ssz * DKd);
  bf16_t* aout = xb;

  {
    int n4 = Mrows * KD / 4;
    cvt_f32_bf16_kernel<<<(n4 + 255) / 256, 256, 0, stream>>>(x, xb, n4);
  }
  {
    int n4 = N1 * KD / 4;
    cvt_f32_bf16_kernel<<<(n4 + 255) / 256, 256, 0, stream>>>(wqkv, wqkvb, n4);
  }
  {
    int n4 = Dsz * KD / 4;
    cvt_f32_bf16_kernel<<<(n4 + 255) / 256, 256, 0, stream>>>(wo, wob, n4);
  }
  rope_tab_kernel<<<(Ssz * 32 + 255) / 256, 256, 0, stream>>>(pos, tab);

  gemm256_qkv_kernel<<<dim3(N1 / 192, Mrows / 256), 512, 0, stream>>>(
      xb, wqkvb, qbuf, kbuf, vtb, tab);

  attn_kernel<<<dim3(16 * 64), 256, 0, stream>>>(qbuf, kbuf, vtb, aout);

  gemm_out_kernel<<<dim3(Dsz / 128, Mrows / 256), 512, 0, stream>>>(
      aout, wob, out);
}

// Round 11
// 178.513 us; speedup vs baseline: 1.1682x; 1.0027x over previous
//
#include <hip/hip_runtime.h>
#include <hip/hip_bf16.h>
#include <math.h>

typedef __bf16 bf16_t;
typedef __attribute__((ext_vector_type(8))) __bf16 bf16x8;
typedef __attribute__((ext_vector_type(4))) __bf16 bf16x4;
typedef __attribute__((ext_vector_type(4))) float f32x4;

#define MFMA_16x16x32(A_, B_, C_) __builtin_amdgcn_mfma_f32_16x16x32_bf16((A_), (B_), (C_), 0, 0, 0)

#define Bsz 4
#define Ssz 2048
#define Dsz 1024
#define Hh 16
#define DKd 64
#define Mrows (Bsz * Ssz)  /* 8192 */
#define N1 (3 * Dsz)       /* 3072 */
#define KD Dsz             /* 1024 */

// ---------------- f32 -> bf16 conversion (x4 vectorized) ----------------
__global__ void cvt_f32_bf16_kernel(const float* __restrict__ src, bf16_t* __restrict__ dst, int n4) {
  int i = blockIdx.x * blockDim.x + threadIdx.x;
  if (i >= n4) return;
  float4 v = reinterpret_cast<const float4*>(src)[i];
  bf16x4 o = {(bf16_t)v.x, (bf16_t)v.y, (bf16_t)v.z, (bf16_t)v.w};
  reinterpret_cast<bf16x4*>(dst)[i] = o;
}

// ---------------- RoPE cos/sin table: [S][32] float2 ----------------
__global__ void rope_tab_kernel(const int* __restrict__ pos, float2* __restrict__ tab) {
  int i = blockIdx.x * blockDim.x + threadIdx.x;
  if (i >= Ssz * 32) return;
  int s = i >> 5, f = i & 31;
  float inv_freq = powf(10000.0f, -(float)(2 * f) / 64.0f);
  float a = (float)pos[s] * inv_freq;
  tab[i] = make_float2(cosf(a), sinf(a));
}

// ============ QKV GEMM: 256(M) x 192(N), BK=64, 8 waves, 8-PHASE (R10) ======
__global__ __launch_bounds__(512, 1) void gemm256_qkv_kernel(
    const bf16_t* __restrict__ A, const bf16_t* __restrict__ Bt,
    bf16_t* __restrict__ qb, bf16_t* __restrict__ kb, bf16_t* __restrict__ vtb,
    const float2* __restrict__ tab) {
  constexpr int NT = KD / 64;  // 16
  __shared__ __align__(16) bf16_t As[2][256 * 64];
  __shared__ __align__(16) bf16_t Bs[2][192 * 64];
  const int t = threadIdx.x;
  const int w = t >> 6, l = t & 63;
  const int lr = l & 15, lk = l >> 4;
  const int rs = lr >> 1;             // read-side swizzle (0..7)
  const int wm = w >> 2, wn = w & 3;  // 2M x 4N waves
  const int m0 = blockIdx.y * 256, n0 = blockIdx.x * 192;

  const int gcol = ((t & 7) ^ ((t >> 4) & 7)) * 8;
  const bf16_t* gA = A + (size_t)(m0 + (t >> 3)) * KD + gcol;
  const bf16_t* gB = Bt + (size_t)(n0 + (t >> 3)) * KD + gcol;

  f32x4 acc[8][3] = {};
  bf16x8 bfv[3][2];

#define LDA_(I_, SB_, KT_)                                                        \
  __builtin_amdgcn_global_load_lds(gA + (size_t)(I_) * 64 * KD + (KT_),           \
                                   &As[SB_][((I_) * 64 + w * 8) * 64], 16, 0, 0)
#define LDB_(I_, SB_, KT_)                                                        \
  __builtin_amdgcn_global_load_lds(gB + (size_t)(I_) * 64 * KD + (KT_),           \
                                   &Bs[SB_][((I_) * 64 + w * 8) * 64], 16, 0, 0)

#define PH(BUF_, P_, STG0_, STG1_, VMW_)                                          \
  do {                                                                            \
    if ((P_) == 0) {                                                              \
      _Pragma("unroll") for (int n_ = 0; n_ < 3; ++n_) {                          \
        const int R_ = wn * 48 + n_ * 16 + lr;                                    \
        bfv[n_][0] = *reinterpret_cast<const bf16x8*>(                            \
            &Bs[BUF_][R_ * 64 + ((lk ^ rs) * 8)]);                                \
        bfv[n_][1] = *reinterpret_cast<const bf16x8*>(                            \
            &Bs[BUF_][R_ * 64 + (((4 + lk) ^ rs) * 8)]);                          \
      }                                                                           \
    }                                                                             \
    bf16x8 af0_[2], af1_[2];                                                      \
    {                                                                             \
      const int Ra_ = wm * 128 + (P_) * 32 + lr;                                  \
      const int Rb_ = Ra_ + 16;                                                   \
      af0_[0] = *reinterpret_cast<const bf16x8*>(&As[BUF_][Ra_ * 64 + ((lk ^ rs) * 8)]);       \
      af0_[1] = *reinterpret_cast<const bf16x8*>(&As[BUF_][Ra_ * 64 + (((4 + lk) ^ rs) * 8)]); \
      af1_[0] = *reinterpret_cast<const bf16x8*>(&As[BUF_][Rb_ * 64 + ((lk ^ rs) * 8)]);       \
      af1_[1] = *reinterpret_cast<const bf16x8*>(&As[BUF_][Rb_ * 64 + (((4 + lk) ^ rs) * 8)]); \
    }                                                                             \
    STG0_;                                                                        \
    STG1_;                                                                        \
    __builtin_amdgcn_s_barrier();                                                 \
    asm volatile("s_waitcnt lgkmcnt(0)" ::: "memory");                            \
    __builtin_amdgcn_sched_barrier(0);                                            \
    __builtin_amdgcn_s_setprio(1);                                                \
    _Pragma("unroll") for (int n_ = 0; n_ < 3; ++n_) {                            \
      acc[(P_)*2][n_] = MFMA_16x16x32(af0_[0], bfv[n_][0], acc[(P_)*2][n_]);      \
      acc[(P_)*2][n_] = MFMA_16x16x32(af0_[1], bfv[n_][1], acc[(P_)*2][n_]);      \
      acc[(P_)*2 + 1][n_] = MFMA_16x16x32(af1_[0], bfv[n_][0], acc[(P_)*2 + 1][n_]); \
      acc[(P_)*2 + 1][n_] = MFMA_16x16x32(af1_[1], bfv[n_][1], acc[(P_)*2 + 1][n_]); \
    }                                                                             \
    __builtin_amdgcn_s_setprio(0);                                                \
    VMW_;                                                                         \
    __builtin_amdgcn_s_barrier();                                                 \
  } while (0)

#define VM4_ do { asm volatile("s_waitcnt vmcnt(4)" ::: "memory"); __builtin_amdgcn_sched_barrier(0); } while (0)
#define VM2_ do { asm volatile("s_waitcnt vmcnt(2)" ::: "memory"); __builtin_amdgcn_sched_barrier(0); } while (0)

#define TILE_(BUF_, KTN_)                                                         \
  do {                                                                            \
    PH(BUF_, 0, LDB_(0, (BUF_) ^ 1, KTN_), LDB_(1, (BUF_) ^ 1, KTN_), (void)0);   \
    PH(BUF_, 1, LDB_(2, (BUF_) ^ 1, KTN_), LDA_(0, (BUF_) ^ 1, KTN_), VM4_);      \
    PH(BUF_, 2, LDA_(2, (BUF_) ^ 1, KTN_), LDA_(1, (BUF_) ^ 1, KTN_), (void)0);   \
    PH(BUF_, 3, LDA_(3, (BUF_) ^ 1, KTN_), (void)0, VM2_);                        \
  } while (0)

  LDB_(0, 0, 0); LDB_(1, 0, 0); LDB_(2, 0, 0);
  LDA_(0, 0, 0); LDA_(2, 0, 0); LDA_(1, 0, 0); LDA_(3, 0, 0);
  asm volatile("s_waitcnt vmcnt(2)" ::: "memory");
  __builtin_amdgcn_s_barrier();

#pragma unroll 1
  for (int tt = 0; tt < NT; tt += 2) {
    const int ktn0 = ((tt + 1) & (NT - 1)) * 64;  // last tile wraps to 0 (dead buf)
    TILE_(0, ktn0);
    const int ktn1 = ((tt + 2) & (NT - 1)) * 64;
    TILE_(1, ktn1);
  }
#undef TILE_
#undef VM4_
#undef VM2_
#undef PH
#undef LDA_
#undef LDB_

  // ---- epilogue: per-n section decode ----
#pragma unroll
  for (int n = 0; n < 3; ++n) {
    const int colbase = n0 + wn * 48 + n * 16;
    const int sect = colbase >> 10;  // 0=q 1=k 2=v
    const int h = (colbase >> 6) & 15;
    const int dk = (colbase & 63) + lr;
    if (sect < 2) {
      bf16_t* dst0 = (sect == 0) ? qb : kb;
#pragma unroll
      for (int m = 0; m < 8; ++m)
#pragma unroll
        for (int r = 0; r < 4; ++r) {
          const int grow = m0 + wm * 128 + m * 16 + lk * 4 + r;
          const int bb = grow >> 11, s = grow & (Ssz - 1);
          const float v = acc[m][n][r];
          const float pv = __shfl_xor(v, 1);
          const float2 cs = tab[(s << 5) | (dk >> 1)];
          float vr = (dk & 1) ? (pv * cs.y + v * cs.x) : (v * cs.x - pv * cs.y);
          if (sect == 0) vr *= 0.125f;
          dst0[((size_t)(bb * Hh + h) * Ssz + s) * DKd + dk] = (bf16_t)vr;
        }
    } else {
#pragma unroll
      for (int m = 0; m < 8; ++m) {
        const int grow0 = m0 + wm * 128 + m * 16 + lk * 4;
        const int bb = grow0 >> 11, s0 = grow0 & (Ssz - 1);
        const bf16x4 ov = {(bf16_t)acc[m][n][0], (bf16_t)acc[m][n][1],
                           (bf16_t)acc[m][n][2], (bf16_t)acc[m][n][3]};
        *reinterpret_cast<bf16x4*>(
            vtb + ((size_t)(bb * Hh + h) * DKd + dk) * Ssz + s0) = ov;
      }
    }
  }
}

// ============ out-proj GEMM: 256(M) x 128(N), BK=64, 8 waves, 8-PHASE =======
// Same counted-vmcnt template as QKV; 6 loads/tile: B0,B1 | A0,A2 | A1,A3 | -.
// Waits: vmcnt(4)@end-ph1 (lands this tile's A-issues 1,3 for ph2/ph3),
// vmcnt(2)@end-ph3 (lands next tile's B0,B1,A0,A2). Never 0 in loop.
__global__ __launch_bounds__(512, 1) void gemm_out_kernel(
    const bf16_t* __restrict__ A, const bf16_t* __restrict__ Bt,
    float* __restrict__ fout) {
  constexpr int NT = KD / 64;  // 16
  __shared__ __align__(16) bf16_t As[2][256 * 64];
  __shared__ __align__(16) bf16_t Bs[2][128 * 64];
  const int t = threadIdx.x;
  const int w = t >> 6, l = t & 63;
  const int lr = l & 15, lk = l >> 4;
  const int rs = lr >> 1;
  const int wm = w >> 2, wn = w & 3;
  const int m0 = blockIdx.y * 256, n0 = blockIdx.x * 128;

  const int gcol = ((t & 7) ^ ((t >> 4) & 7)) * 8;
  const bf16_t* gA = A + (size_t)(m0 + (t >> 3)) * KD + gcol;
  const bf16_t* gB = Bt + (size_t)(n0 + (t >> 3)) * KD + gcol;

  f32x4 acc[8][2] = {};
  bf16x8 bfv[2][2];

#define OLDA_(I_, SB_, KT_)                                                       \
  __builtin_amdgcn_global_load_lds(gA + (size_t)(I_) * 64 * KD + (KT_),           \
                                   &As[SB_][((I_) * 64 + w * 8) * 64], 16, 0, 0)
#define OLDB_(I_, SB_, KT_)                                                       \
  __builtin_amdgcn_global_load_lds(gB + (size_t)(I_) * 64 * KD + (KT_),           \
                                   &Bs[SB_][((I_) * 64 + w * 8) * 64], 16, 0, 0)

#define OPH(BUF_, P_, STG0_, STG1_, VMW_)                                         \
  do {                                                                            \
    if ((P_) == 0) {                                                              \
      _Pragma("unroll") for (int n_ = 0; n_ < 2; ++n_) {                          \
        const int R_ = wn * 32 + n_ * 16 + lr;                                    \
        bfv[n_][0] = *reinterpret_cast<const bf16x8*>(                            \
            &Bs[BUF_][R_ * 64 + ((lk ^ rs) * 8)]);                                \
        bfv[n_][1] = *reinterpret_cast<const bf16x8*>(                            \
            &Bs[BUF_][R_ * 64 + (((4 + lk) ^ rs) * 8)]);                          \
      }                                                                           \
    }                                                                             \
    bf16x8 af0_[2], af1_[2];                                                      \
    {                                                                             \
      const int Ra_ = wm * 128 + (P_) * 32 + lr;                                  \
      const int Rb_ = Ra_ + 16;                                                   \
      af0_[0] = *reinterpret_cast<const bf16x8*>(&As[BUF_][Ra_ * 64 + ((lk ^ rs) * 8)]);       \
      af0_[1] = *reinterpret_cast<const bf16x8*>(&As[BUF_][Ra_ * 64 + (((4 + lk) ^ rs) * 8)]); \
      af1_[0] = *reinterpret_cast<const bf16x8*>(&As[BUF_][Rb_ * 64 + ((lk ^ rs) * 8)]);       \
      af1_[1] = *reinterpret_cast<const bf16x8*>(&As[BUF_][Rb_ * 64 + (((4 + lk) ^ rs) * 8)]); \
    }                                                                             \
    STG0_;                                                                        \
    STG1_;                                                                        \
    __builtin_amdgcn_s_barrier();                                                 \
    asm volatile("s_waitcnt lgkmcnt(0)" ::: "memory");                            \
    __builtin_amdgcn_sched_barrier(0);                                            \
    __builtin_amdgcn_s_setprio(1);                                                \
    _Pragma("unroll") for (int n_ = 0; n_ < 2; ++n_) {                            \
      acc[(P_)*2][n_] = MFMA_16x16x32(af0_[0], bfv[n_][0], acc[(P_)*2][n_]);      \
      acc[(P_)*2][n_] = MFMA_16x16x32(af0_[1], bfv[n_][1], acc[(P_)*2][n_]);      \
      acc[(P_)*2 + 1][n_] = MFMA_16x16x32(af1_[0], bfv[n_][0], acc[(P_)*2 + 1][n_]); \
      acc[(P_)*2 + 1][n_] = MFMA_16x16x32(af1_[1], bfv[n_][1], acc[(P_)*2 + 1][n_]); \
    }                                                                             \
    __builtin_amdgcn_s_setprio(0);                                                \
    VMW_;                                                                         \
    __builtin_amdgcn_s_barrier();                                                 \
  } while (0)

#define OVM4_ do { asm volatile("s_waitcnt vmcnt(4)" ::: "memory"); __builtin_amdgcn_sched_barrier(0); } while (0)
#define OVM2_ do { asm volatile("s_waitcnt vmcnt(2)" ::: "memory"); __builtin_amdgcn_sched_barrier(0); } while (0)

#define OTILE_(BUF_, KTN_)                                                        \
  do {                                                                            \
    OPH(BUF_, 0, OLDB_(0, (BUF_) ^ 1, KTN_), OLDB_(1, (BUF_) ^ 1, KTN_), (void)0);\
    OPH(BUF_, 1, OLDA_(0, (BUF_) ^ 1, KTN_), OLDA_(2, (BUF_) ^ 1, KTN_), OVM4_);  \
    OPH(BUF_, 2, OLDA_(1, (BUF_) ^ 1, KTN_), OLDA_(3, (BUF_) ^ 1, KTN_), (void)0);\
    OPH(BUF_, 3, (void)0, (void)0, OVM2_);                                        \
  } while (0)

  OLDB_(0, 0, 0); OLDB_(1, 0, 0);
  OLDA_(0, 0, 0); OLDA_(2, 0, 0); OLDA_(1, 0, 0); OLDA_(3, 0, 0);
  asm volatile("s_waitcnt vmcnt(2)" ::: "memory");
  __builtin_amdgcn_s_barrier();

#pragma unroll 1
  for (int tt = 0; tt < NT; tt += 2) {
    const int ktn0 = ((tt + 1) & (NT - 1)) * 64;
    OTILE_(0, ktn0);
    const int ktn1 = ((tt + 2) & (NT - 1)) * 64;
    OTILE_(1, ktn1);
  }
#undef OTILE_
#undef OVM4_
#undef OVM2_
#undef OPH
#undef OLDA_
#undef OLDB_

#pragma unroll
  for (int m = 0; m < 8; ++m)
#pragma unroll
    for (int r = 0; r < 4; ++r) {
      const int grow = m0 + wm * 128 + m * 16 + lk * 4 + r;
      float* op = fout + (size_t)grow * Dsz + n0 + wn * 32 + lr;
      op[0] = acc[m][0][r];
      op[16] = acc[m][1][r];
    }
}

// ---------------- causal flash attention: 1 barrier/KV-tile (dbuf K/V LDS) --
// Issue next-tile global->reg loads BEFORE compute (latency hides under
// QK^T/softmax/PV), ds_write to the idle buffer AFTER compute (implicit
// vmcnt wait), single barrier. WAR safe: buffer written in iter i was last
// read in iter i-1, behind that barrier.
__global__ __launch_bounds__(256, 3) void attn_kernel(
    const bf16_t* __restrict__ qb, const bf16_t* __restrict__ kb,
    const bf16_t* __restrict__ vtb, bf16_t* __restrict__ aout) {
  __shared__ __align__(16) bf16_t Ks[2][64 * 64];
  __shared__ __align__(16) bf16_t Vs[2][64 * 64];
  const int t = threadIdx.x, w = t >> 6, l = t & 63;
  const int lr = l & 15, lk = l >> 4;
  const int bid = blockIdx.x;
  const int bh = (bid & 7) * 8 + ((bid >> 3) & 7);
  const int qt = 15 - (bid >> 6);  // heavy-first
  const int q0 = qt * 128;
  const int sub0 = q0 + w * 32;

  const bf16_t* qbase = qb + ((size_t)bh * Ssz + sub0) * DKd;
  bf16x8 qf[2][2];
#pragma unroll
  for (int s = 0; s < 2; ++s) {
    qf[s][0] = *reinterpret_cast<const bf16x8*>(qbase + (s * 16 + lr) * DKd + lk * 8);
    qf[s][1] = *reinterpret_cast<const bf16x8*>(qbase + (s * 16 + lr) * DKd + 32 + lk * 8);
  }

  f32x4 o[2][4] = {};
  float mrow[2] = {-INFINITY, -INFINITY};
  float lsum[2] = {0.f, 0.f};

  const int srow = t >> 2;
  const int scc = (t & 3) * 2;
  const bf16_t* kg = kb + ((size_t)bh * Ssz + srow) * DKd + scc * 8;
  const bf16_t* vg = vtb + ((size_t)bh * DKd + srow) * Ssz + scc * 8;
  // LDS write offsets (element) within a buffer
  const int koff0 = srow * 64 + ((scc ^ (srow & 7)) * 8);
  const int koff1 = srow * 64 + (((scc + 1) ^ (srow & 7)) * 8);
  int voff[4];
#pragma unroll
  for (int u = 0; u < 2; ++u) {
    const int c = scc + u;
    const int B = 32 * (c >> 2) + 16 * (c & 1) + 4 * ((c & 3) >> 1);
    const int ch = B >> 3, off = B & 7;
    voff[2 * u] = srow * 64 + ((ch ^ (srow & 7)) * 8) + off;
    voff[2 * u + 1] = srow * 64 + (((ch + 1) ^ (srow & 7)) * 8) + off;
  }

  const int kvend = q0 + 128;
  bf16x8 pk0 = *reinterpret_cast<const bf16x8*>(kg);
  bf16x8 pk1 = *reinterpret_cast<const bf16x8*>(kg + 8);
  bf16x8 pv0 = *reinterpret_cast<const bf16x8*>(vg);
  bf16x8 pv1 = *reinterpret_cast<const bf16x8*>(vg + 8);

  // prologue: tile 0 into buf 0
  *reinterpret_cast<bf16x8*>(&Ks[0][koff0]) = pk0;
  *reinterpret_cast<bf16x8*>(&Ks[0][koff1]) = pk1;
  *reinterpret_cast<bf16x4*>(&Vs[0][voff[0]]) = __builtin_shufflevector(pv0, pv0, 0, 1, 2, 3);
  *reinterpret_cast<bf16x4*>(&Vs[0][voff[1]]) = __builtin_shufflevector(pv0, pv0, 4, 5, 6, 7);
  *reinterpret_cast<bf16x4*>(&Vs[0][voff[2]]) = __builtin_shufflevector(pv1, pv1, 0, 1, 2, 3);
  *reinterpret_cast<bf16x4*>(&Vs[0][voff[3]]) = __builtin_shufflevector(pv1, pv1, 4, 5, 6, 7);
  __syncthreads();

  for (int kv = 0; kv < kvend; kv += 64) {
    const int buf = (kv >> 6) & 1;
    const bool more = (kv + 64 < kvend);
    if (more) {  // issue next-tile loads; land under this tile's compute
      pk0 = *reinterpret_cast<const bf16x8*>(kg + (size_t)(kv + 64) * DKd);
      pk1 = *reinterpret_cast<const bf16x8*>(kg + (size_t)(kv + 64) * DKd + 8);
      pv0 = *reinterpret_cast<const bf16x8*>(vg + kv + 64);
      pv1 = *reinterpret_cast<const bf16x8*>(vg + kv + 64 + 8);
    }
    const bf16_t* Kb = Ks[buf];
    const bf16_t* Vb = Vs[buf];
#pragma unroll
    for (int s = 0; s < 2; ++s) {
      const int subrow = sub0 + s * 16;
      if (kv > subrow + 15) continue;
      f32x4 sa[4];
#pragma unroll
      for (int n = 0; n < 4; ++n) {
        const int R = n * 16 + lr;
        const bf16x8 a0 = *reinterpret_cast<const bf16x8*>(Kb + R * 64 + ((lk ^ (R & 7)) * 8));
        const bf16x8 a1 = *reinterpret_cast<const bf16x8*>(Kb + R * 64 + (((lk + 4) ^ (R & 7)) * 8));
        f32x4 z = {};
        z = MFMA_16x16x32(a0, qf[s][0], z);
        z = MFMA_16x16x32(a1, qf[s][1], z);
        sa[n] = z;
      }
      if (kv + 63 > subrow) {
        const int qrow = subrow + lr;
        const int kbase = kv + lk * 4;
#pragma unroll
        for (int n = 0; n < 4; ++n)
#pragma unroll
          for (int r = 0; r < 4; ++r)
            if (kbase + n * 16 + r > qrow) sa[n][r] = -INFINITY;
      }
      float mx = fmaxf(fmaxf(fmaxf(sa[0][0], sa[0][1]), fmaxf(sa[0][2], sa[0][3])),
                       fmaxf(fmaxf(sa[1][0], sa[1][1]), fmaxf(sa[1][2], sa[1][3])));
      mx = fmaxf(mx, fmaxf(fmaxf(fmaxf(sa[2][0], sa[2][1]), fmaxf(sa[2][2], sa[2][3])),
                           fmaxf(fmaxf(sa[3][0], sa[3][1]), fmaxf(sa[3][2], sa[3][3]))));
      mx = fmaxf(mx, __shfl_xor(mx, 16));
      mx = fmaxf(mx, __shfl_xor(mx, 32));
      const float mnew = fmaxf(mrow[s], mx);
      const float scl = __expf(mrow[s] - mnew);
      mrow[s] = mnew;
      float ps = 0.f;
#pragma unroll
      for (int n = 0; n < 4; ++n)
#pragma unroll
        for (int r = 0; r < 4; ++r) {
          const float p = __expf(sa[n][r] - mnew);
          sa[n][r] = p;
          ps += p;
        }
      lsum[s] = lsum[s] * scl + ps;
#pragma unroll
      for (int n = 0; n < 4; ++n)
#pragma unroll
        for (int r = 0; r < 4; ++r) o[s][n][r] *= scl;
      bf16x8 pb0, pb1;
#pragma unroll
      for (int r = 0; r < 4; ++r) {
        pb0[r] = (bf16_t)sa[0][r];
        pb0[4 + r] = (bf16_t)sa[1][r];
        pb1[r] = (bf16_t)sa[2][r];
        pb1[4 + r] = (bf16_t)sa[3][r];
      }
#pragma unroll
      for (int n = 0; n < 4; ++n) {
        const int R = n * 16 + lr;
        const bf16x8 v0 = *reinterpret_cast<const bf16x8*>(Vb + R * 64 + ((lk ^ (R & 7)) * 8));
        const bf16x8 v1 = *reinterpret_cast<const bf16x8*>(Vb + R * 64 + (((lk + 4) ^ (R & 7)) * 8));
        o[s][n] = MFMA_16x16x32(v0, pb0, o[s][n]);
        o[s][n] = MFMA_16x16x32(v1, pb1, o[s][n]);
      }
    }
    if (more) {  // write next tile to idle buffer (implicit vmcnt wait)
      bf16_t* Kn = Ks[buf ^ 1];
      bf16_t* Vn = Vs[buf ^ 1];
      *reinterpret_cast<bf16x8*>(&Kn[koff0]) = pk0;
      *reinterpret_cast<bf16x8*>(&Kn[koff1]) = pk1;
      *reinterpret_cast<bf16x4*>(&Vn[voff[0]]) = __builtin_shufflevector(pv0, pv0, 0, 1, 2, 3);
      *reinterpret_cast<bf16x4*>(&Vn[voff[1]]) = __builtin_shufflevector(pv0, pv0, 4, 5, 6, 7);
      *reinterpret_cast<bf16x4*>(&Vn[voff[2]]) = __builtin_shufflevector(pv1, pv1, 0, 1, 2, 3);
      *reinterpret_cast<bf16x4*>(&Vn[voff[3]]) = __builtin_shufflevector(pv1, pv1, 4, 5, 6, 7);
      __syncthreads();
    }
  }
  const int b_ = bh >> 4, h_ = bh & 15;
#pragma unroll
  for (int s = 0; s < 2; ++s) {
    float sm = lsum[s];
    sm += __shfl_xor(sm, 16);
    sm += __shfl_xor(sm, 32);
    const float inv = 1.0f / sm;
    const int qrow = sub0 + s * 16 + lr;
    bf16_t* op = aout + ((size_t)b_ * Ssz + qrow) * Dsz + h_ * DKd + lk * 4;
#pragma unroll
    for (int n = 0; n < 4; ++n) {
      const bf16x4 ov = {(bf16_t)(o[s][n][0] * inv), (bf16_t)(o[s][n][1] * inv),
                         (bf16_t)(o[s][n][2] * inv), (bf16_t)(o[s][n][3] * inv)};
      *reinterpret_cast<bf16x4*>(op + n * 16) = ov;
    }
  }
}

extern "C" void kernel_launch(void* const* d_in, const int* in_sizes, int n_in,
                              void* d_out, int out_size, void* d_ws, size_t ws_size,
                              hipStream_t stream) {
  const float* x = (const float*)d_in[0];
  const int* pos = (const int*)d_in[1];
  const float* wqkv = (const float*)d_in[2];
  const float* wo = (const float*)d_in[3];
  float* out = (float*)d_out;

  bf16_t* xb = (bf16_t*)d_ws;
  bf16_t* wqkvb = xb + (size_t)Mrows * KD;
  bf16_t* wob = wqkvb + (size_t)N1 * KD;
  bf16_t* qbuf = wob + (size_t)Dsz * KD;
  bf16_t* kbuf = qbuf + (size_t)64 * Ssz * DKd;
  bf16_t* vtb = kbuf + (size_t)64 * Ssz * DKd;
  float2* tab = (float2*)(vtb + (size_t)64 * Ssz * DKd);
  bf16_t* aout = xb;

  {
    int n4 = Mrows * KD / 4;
    cvt_f32_bf16_kernel<<<(n4 + 255) / 256, 256, 0, stream>>>(x, xb, n4);
  }
  {
    int n4 = N1 * KD / 4;
    cvt_f32_bf16_kernel<<<(n4 + 255) / 256, 256, 0, stream>>>(wqkv, wqkvb, n4);
  }
  {
    int n4 = Dsz * KD / 4;
    cvt_f32_bf16_kernel<<<(n4 + 255) / 256, 256, 0, stream>>>(wo, wob, n4);
  }
  rope_tab_kernel<<<(Ssz * 32 + 255) / 256, 256, 0, stream>>>(pos, tab);

  gemm256_qkv_kernel<<<dim3(N1 / 192, Mrows / 256), 512, 0, stream>>>(
      xb, wqkvb, qbuf, kbuf, vtb, tab);

  attn_kernel<<<dim3(16 * 64), 256, 0, stream>>>(qbuf, kbuf, vtb, aout);

  gemm_out_kernel<<<dim3(Dsz / 128, Mrows / 256), 512, 0, stream>>>(
      aout, wob, out);
}